// Round 20
// baseline (119.453 us; speedup 1.0000x reference)
//
#include <hip/hip_runtime.h>

#define NLAT 255
#define NLON 256
#define NPIX 49152
#define MMAX 129
#define MCS  258      // 2*MMAX
#define NTBL 65       // distinct ring geometries
#define TROWS 264     // Ttab3 padded mcs rows (258..263 zero)

typedef unsigned short ushort_t;
typedef __attribute__((ext_vector_type(8)))  short  bf16x8;
typedef __attribute__((ext_vector_type(4)))  short  short4v;
typedef __attribute__((ext_vector_type(16))) float  f32x16;
typedef __attribute__((ext_vector_type(4)))  float  float4v;

__device__ __forceinline__ ushort_t f2bf(float f) {
    union { float f; unsigned u; } v; v.f = f;
    unsigned r = v.u + 0x7FFFu + ((v.u >> 16) & 1u);   // RTNE
    return (ushort_t)(r >> 16);
}
__device__ __forceinline__ float bf2f(ushort_t h) {
    union { unsigned u; float f; } v; v.u = ((unsigned)h) << 16;
    return v.f;
}

// ---------------- kernel 0a: weight prep (fragment-major) --------------
// pctwF[m][kg(32)][l(256)][j(8)] bf16 = pct[m][l][kg*8+j] * w[k].
__global__ __launch_bounds__(256) void prepK(const float* __restrict__ pct,
                                             const float* __restrict__ w,
                                             ushort_t* __restrict__ pctwF) {
    const int m  = blockIdx.x;           // 0..128
    const int l0 = blockIdx.y * 32;
    const int t  = threadIdx.x;          // k
    const float wk = (t < NLAT) ? w[t] : 0.f;
    const int kg = t >> 3, j = t & 7;
    for (int l = l0; l < l0 + 32; ++l) {
        float v = 0.f;
        if (l < NLAT && t < NLAT)
            v = pct[((size_t)m * NLAT + l) * NLAT + t] * wk;
        pctwF[(((size_t)m * 32 + kg) * 256 + l) * 8 + j] = f2bf(v);
    }
}

// ---------------- kernel 0b: trig table -------------------------------
// Ttab3[tbl][p>>6][(p>>3)&7][mcs(264)][p&7] bf16, mask baked in.
__global__ __launch_bounds__(256) void trigK(const float* __restrict__ phase,
                                             const float* __restrict__ mask,
                                             ushort_t* __restrict__ Ttab3) {
    const int tt  = blockIdx.x;          // 0..64
    const int mcs = blockIdx.y;          // 0..263
    const int p   = threadIdx.x;         // 0..255
    const int r   = (tt < 63) ? tt : (tt == 63 ? 63 : 64);
    float val = 0.f;
    if (mcs < MCS) {
        float ph = phase[r * NLON + p];
        float mk = mask[r * NLON + p];
        float fm = (float)(mcs >> 1);
        float s, c;
        __sincosf(ph * fm, &s, &c);
        val = (mcs & 1) ? (-s * mk) : (c * mk);
    }
    const int pcc = p >> 6, c = (p >> 3) & 7, j = p & 7;
    Ttab3[((((size_t)tt * 4 + pcc) * 8 + c) * TROWS + mcs) * 8 + j] = f2bf(val);
}

// ---------------- kernel 1: stage A (ring DFT via MFMA) ----------------
// r14 structure + wcol-cut + NEW 2-deep x-register pipeline (rxA/rxB):
// chunk c stores x-data loaded at chunk c-1 (vmcnt wait ~free: 36 younger
// loads issued since) and issues the load for c+2. Removes the ~900-cyc
// per-chunk vmcnt(0) stall on fresh x-loads.
__global__ __launch_bounds__(256, 2) void stageA(const float* __restrict__ x,
                                                 const int* __restrict__ ring_index,
                                                 const ushort_t* __restrict__ Ttab3,
                                                 ushort_t* __restrict__ f1) {
    __shared__ __align__(16) ushort_t Rs[2][64 * 72];   // 18432 B; Olds alias

    const int b0 = blockIdx.x * 64;      // bc tile base
    const int r  = blockIdx.y;           // ring
    const int i1 = r + 1;
    const int nph = (i1 < 64) ? 4 * i1 : (i1 <= 192 ? 256 : 4 * (256 - i1));
    const int tbl = (i1 < 64) ? r : (i1 <= 192 ? (63 + (((i1 - 63) & 1) ^ 1)) : 254 - r);
    const int base = ring_index[r * NLON];
    const int nchunks = (nph + 63) >> 6;

    const int t    = threadIdx.x;
    const int lane = t & 63;
    const int wid  = t >> 6;
    const int wrow = wid >> 1, wcol = wid & 1;
    const int lg   = lane >> 5;
    const int lc   = lane & 31;

    f32x16 acc[5];
#pragma unroll
    for (int tau = 0; tau < 5; ++tau)
#pragma unroll
        for (int q = 0; q < 16; ++q) acc[tau][q] = 0.f;

    int trow[5];
#pragma unroll
    for (int tau = 0; tau < 5; ++tau) {
        int rr = tau * 64 + wcol * 32 + lc;
        trow[tau] = rr > (TROWS - 1) ? (TROWS - 1) : rr;
    }

    float4v rxA[4], rxB[4];
    const int p0 = (t & 15) * 4;
    auto ldX = [&](int pc, float4v* rx) {
        const bool ok = (pc + p0) < nph;
#pragma unroll
        for (int pass = 0; pass < 4; ++pass) {
            int bc = (t >> 4) + pass * 16;
            float4v v = {0.f, 0.f, 0.f, 0.f};
            if (ok) v = *(const float4v*)(x + (size_t)(b0 + bc) * NPIX + base + pc + p0);
            rx[pass] = v;
        }
    };
    auto stX = [&](const float4v* rx, ushort_t* dst) {
#pragma unroll
        for (int pass = 0; pass < 4; ++pass) {
            int bc = (t >> 4) + pass * 16;
            short4v h;
            h[0] = (short)f2bf(rx[pass][0]); h[1] = (short)f2bf(rx[pass][1]);
            h[2] = (short)f2bf(rx[pass][2]); h[3] = (short)f2bf(rx[pass][3]);
            *(short4v*)(dst + bc * 72 + p0) = h;
        }
    };

    // chunk body: B-prefetch(c) -> issue x(c+2) -> MFMA(c) -> store x(c+1)
    auto CHUNK = [&](int c, float4v* rxStore, float4v* rxFill) {
        const ushort_t* slab = Ttab3 + (size_t)(tbl * 4 + c) * (8 * TROWS * 8);
        bf16x8 bfr[4][5];
#pragma unroll
        for (int ks = 0; ks < 4; ++ks) {
            const ushort_t* bcol = slab + (size_t)(ks * 2 + lg) * (TROWS * 8);
#pragma unroll
            for (int tau = 0; tau < 4; ++tau)
                bfr[ks][tau] = *(const bf16x8*)(bcol + trow[tau] * 8);
            if (wcol == 0)
                bfr[ks][4] = *(const bf16x8*)(bcol + trow[4] * 8);
        }
        if (c + 2 < nchunks) ldX((c + 2) << 6, rxFill);

        const ushort_t* Rcur = Rs[c & 1];
#pragma unroll
        for (int ks = 0; ks < 4; ++ks) {
            bf16x8 a = *(const bf16x8*)(Rcur + (wrow * 32 + lc) * 72 + ks * 16 + lg * 8);
#pragma unroll
            for (int tau = 0; tau < 4; ++tau)
                acc[tau] = __builtin_amdgcn_mfma_f32_32x32x16_bf16(a, bfr[ks][tau], acc[tau], 0, 0, 0);
            if (wcol == 0)
                acc[4] = __builtin_amdgcn_mfma_f32_32x32x16_bf16(a, bfr[ks][4], acc[4], 0, 0, 0);
        }
        if (c + 1 < nchunks) stX(rxStore, Rs[(c + 1) & 1]);
        __syncthreads();
    };

    // prologue: x(0) -> Rs[0] (one exposed latency round), issue x(1)
    ldX(0, rxA);
    stX(rxA, Rs[0]);
    ldX(64, rxB);
    __syncthreads();

    for (int c = 0; c < nchunks; c += 2) {
        CHUNK(c, rxB, rxA);                    // store chunk c+1 (in rxB), refill rxA with c+2
        if (c + 1 < nchunks) CHUNK(c + 1, rxA, rxB);
    }

    // ---- epilogue: per tau, acc -> Olds[mcs][bc] -> coalesced f1 ----
    ushort_t* Olds = Rs[0];
#pragma unroll
    for (int tau = 0; tau < 5; ++tau) {
        __syncthreads();
        {
            const int mcsl = wcol * 32 + lc;
#pragma unroll
            for (int q = 0; q < 16; ++q) {
                int bcl = wrow * 32 + 4 * lg + (q & 3) + 8 * (q >> 2);
                Olds[mcsl * 72 + bcl] = f2bf(acc[tau][q]);
            }
        }
        __syncthreads();
        {
            int row = t >> 2;
            int mcs = tau * 64 + row;
            if (mcs < MCS) {
                int m = mcs >> 1, n = mcs & 1;
                size_t gbase = ((size_t)m * NLAT + r) * 512 + n * 256 + b0 + (t & 3) * 16;
#pragma unroll
                for (int j = 0; j < 2; ++j) {
                    bf16x8 v = *(const bf16x8*)(Olds + row * 72 + (t & 3) * 16 + j * 8);
                    *(bf16x8*)(f1 + gbase + j * 8) = v;
                }
            }
        }
    }
}

// ---------------- kernel 2: transpose f1 -> f1tF (fragment-major) -------
// f1tF[m][kg(32)][bc2(512)][j(8)]
__global__ __launch_bounds__(256) void transK(const ushort_t* __restrict__ f1,
                                              ushort_t* __restrict__ f1tF) {
    __shared__ __align__(16) ushort_t T[64][72];
    const int m  = blockIdx.x;
    const int k0 = blockIdx.y * 64;
    const int b0 = blockIdx.z * 64;
    const int t  = threadIdx.x;
#pragma unroll
    for (int it = 0; it < 2; ++it) {
        int id = t + it * 256;
        int kk = id >> 3, ch = id & 7;
        int k  = k0 + kk;
        bf16x8 v = {0,0,0,0,0,0,0,0};
        if (k < NLAT)
            v = *(const bf16x8*)(f1 + ((size_t)m * NLAT + k) * 512 + b0 + ch * 8);
        *(bf16x8*)(&T[kk][ch * 8]) = v;
    }
    __syncthreads();
#pragma unroll
    for (int it = 0; it < 2; ++it) {
        int id  = t + it * 256;
        int bb  = id & 63, ch8 = id >> 6;
        bf16x8 v;
#pragma unroll
        for (int j = 0; j < 8; ++j) v[j] = T[ch8 * 8 + j][bb];
        *(bf16x8*)(f1tF + (((size_t)m * 32 + (k0 >> 3) + ch8) * 512 + b0 + bb) * 8) = v;
    }
}

// ---------------- kernel 3: stage B v3 (m97-style gload_lds GEMM) -------
__global__ __launch_bounds__(256, 3) void stageB(const ushort_t* __restrict__ f1tF,
                                                 const ushort_t* __restrict__ pctwF,
                                                 ushort_t* __restrict__ otmp) {
    __shared__ __align__(16) ushort_t SB[24576];  // As[2][4096] | Ws[2][8192] u16
    ushort_t* Es = SB;                            // epilogue alias

    const int id = blockIdx.x;
    const int m  = ((id >> 5) << 3) | (id & 7);
    if (m >= MMAX) return;
    const int b2t = ((id >> 3) & 3) * 128;

    const int t    = threadIdx.x;
    const int lane = t & 63;
    const int wid  = t >> 6;
    const int wrow = wid >> 1, wlcol = wid & 1;
    const int lg   = lane >> 5, lc = lane & 31;

    f32x16 acc[2][4];
#pragma unroll
    for (int i = 0; i < 2; ++i)
#pragma unroll
        for (int j = 0; j < 4; ++j)
#pragma unroll
            for (int q = 0; q < 16; ++q) acc[i][j][q] = 0.f;

    const ushort_t* aSrc = f1tF  + (size_t)m * 32 * 512 * 8;
    const ushort_t* wSrc = pctwF + (size_t)m * 32 * 256 * 8;

    auto STAGE = [&](int buf, int c) {
#pragma unroll
        for (int u = 0; u < 2; ++u) {
            int sA   = wid * 2 + u;
            int kg   = c * 4 + (sA >> 1);
            int half = sA & 1;
            const ushort_t* src = aSrc + ((size_t)kg * 512 + b2t + half * 64) * 8 + lane * 8;
            __builtin_amdgcn_global_load_lds(
                (const __attribute__((address_space(1))) void*)src,
                (__attribute__((address_space(3))) void*)(SB + buf * 4096 + sA * 512),
                16, 0, 0);
        }
#pragma unroll
        for (int u = 0; u < 4; ++u) {
            int sW = wid * 4 + u;
            int kg = c * 4 + (sW >> 2);
            int q  = sW & 3;
            const ushort_t* src = wSrc + ((size_t)kg * 256 + q * 64) * 8 + lane * 8;
            __builtin_amdgcn_global_load_lds(
                (const __attribute__((address_space(1))) void*)src,
                (__attribute__((address_space(3))) void*)(SB + 8192 + buf * 8192 + sW * 512),
                16, 0, 0);
        }
    };

    STAGE(0, 0);
    __syncthreads();
    int buf = 0;
    for (int c = 0; c < 8; ++c, buf ^= 1) {
        if (c + 1 < 8) STAGE(buf ^ 1, c + 1);
        const ushort_t* A = SB + buf * 4096;
        const ushort_t* W = SB + 8192 + buf * 8192;
#pragma unroll
        for (int ks = 0; ks < 2; ++ks) {
            const int kgl = ks * 2 + lg;
            bf16x8 a0 = *(const bf16x8*)(A + (kgl * 128 + wrow * 64 + lc) * 8);
            bf16x8 a1 = *(const bf16x8*)(A + (kgl * 128 + wrow * 64 + 32 + lc) * 8);
#pragma unroll
            for (int jj = 0; jj < 4; ++jj) {
                bf16x8 b = *(const bf16x8*)(W + (kgl * 256 + wlcol * 128 + jj * 32 + lc) * 8);
                acc[0][jj] = __builtin_amdgcn_mfma_f32_32x32x16_bf16(a0, b, acc[0][jj], 0, 0, 0);
                acc[1][jj] = __builtin_amdgcn_mfma_f32_32x32x16_bf16(a1, b, acc[1][jj], 0, 0, 0);
            }
        }
        __syncthreads();
    }

#pragma unroll
    for (int h = 0; h < 2; ++h) {
        if (h) __syncthreads();
        if (wlcol == h) {
#pragma unroll
            for (int i = 0; i < 2; ++i)
#pragma unroll
                for (int jj = 0; jj < 4; ++jj)
#pragma unroll
                    for (int q = 0; q < 16; ++q) {
                        int bl = wrow * 64 + i * 32 + 4 * lg + (q & 3) + 8 * (q >> 2);
                        Es[bl * 136 + jj * 32 + lc] = f2bf(acc[i][jj][q]);
                    }
        }
        __syncthreads();
#pragma unroll
        for (int it = 0; it < 8; ++it) {
            int id2 = t + it * 256;
            int row = id2 >> 4, ch = id2 & 15;
            bf16x8 v = *(const bf16x8*)(Es + row * 136 + ch * 8);
            *(bf16x8*)(otmp + (((size_t)m * 512 + b2t + row) << 8) + h * 128 + ch * 8) = v;
        }
    }
}

// ---------------- kernel 4: permute to out[bc][l][m][n] ----------------
__global__ __launch_bounds__(256) void permuteK(const ushort_t* __restrict__ otmp,
                                                float* __restrict__ out) {
    __shared__ ushort_t L[MCS * 66];
    const int bc = blockIdx.x;
    const int l0 = blockIdx.y * 64;
    const int t  = threadIdx.x;
    const int ll = t & 63;
    const int l  = l0 + ll;
#pragma unroll 4
    for (int it = 0; it < 65; ++it) {
        int mn = (t >> 6) + it * 4;
        if (mn < MCS) {
            int mm = mn >> 1, n = mn & 1;
            ushort_t v = 0;
            if (l < NLAT)
                v = otmp[(((size_t)mm * 512 + n * 256 + bc) << 8) + l];
            L[mn * 66 + ll] = v;
        }
    }
    __syncthreads();
    for (int ll2 = 0; ll2 < 64; ++ll2) {
        int lo = l0 + ll2;
        if (lo >= NLAT) break;
        size_t rowb = ((size_t)bc * NLAT + lo) * MCS;
        out[rowb + t] = bf2f(L[t * 66 + ll2]);
        if (t < 2)
            out[rowb + 256 + t] = bf2f(L[(256 + t) * 66 + ll2]);
    }
}

extern "C" void kernel_launch(void* const* d_in, const int* in_sizes, int n_in,
                              void* d_out, int out_size, void* d_ws, size_t ws_size,
                              hipStream_t stream) {
    const float* x          = (const float*)d_in[0];
    const float* pct        = (const float*)d_in[1];
    const float* w          = (const float*)d_in[2];
    const int*   ring_index = (const int*)d_in[3];
    const float* ring_mask  = (const float*)d_in[4];
    const float* phase      = (const float*)d_in[5];
    float* out = (float*)d_out;

    // Buffer plan (NO intra-launch hazards):
    //   ws   : otmp @ 0; f1 @ 33,552,384 (otmp tail overlaps dead f1 head).
    //   d_out: f1tF @ 0; pctwF @ 33,816,576; Ttab3 @ 50,724,864 — all dead
    //          before permuteK overwrites d_out with the real output.
    char* wsb = (char*)d_ws;
    char* ob  = (char*)d_out;
    ushort_t* otmp  = (ushort_t*)wsb;
    ushort_t* f1    = (ushort_t*)(wsb + 33552384);
    ushort_t* f1tF  = (ushort_t*)ob;
    ushort_t* pctwF = (ushort_t*)(ob + 33816576);
    ushort_t* Ttab3 = (ushort_t*)(ob + 50724864);

    prepK   <<<dim3(MMAX, 8),     256, 0, stream>>>(pct, w, pctwF);
    trigK   <<<dim3(NTBL, TROWS), 256, 0, stream>>>(phase, ring_mask, Ttab3);
    stageA  <<<dim3(4, NLAT),     256, 0, stream>>>(x, ring_index, Ttab3, f1);
    transK  <<<dim3(MMAX, 4, 8),  256, 0, stream>>>(f1, f1tF);
    stageB  <<<dim3(544),         256, 0, stream>>>(f1tF, pctwF, otmp);
    permuteK<<<dim3(256, 4),      256, 0, stream>>>(otmp, out);
}

// Round 21
// 118.575 us; speedup vs baseline: 1.0074x; 1.0074x over previous
//
#include <hip/hip_runtime.h>

#define NLAT 255
#define NLON 256
#define NPIX 49152
#define MMAX 129
#define MCS  258      // 2*MMAX
#define NTBL 65       // distinct ring geometries
#define TROWS 264     // Ttab3 padded mcs rows (258..263 zero)
#define NPREP (MMAX * 16)   // prep sub-blocks in fused kernel

typedef unsigned short ushort_t;
typedef __attribute__((ext_vector_type(8)))  short  bf16x8;
typedef __attribute__((ext_vector_type(4)))  short  short4v;
typedef __attribute__((ext_vector_type(16))) float  f32x16;
typedef __attribute__((ext_vector_type(4)))  float  float4v;
typedef __attribute__((ext_vector_type(4), aligned(4))) float float4u;

__device__ __forceinline__ ushort_t f2bf(float f) {
    union { float f; unsigned u; } v; v.f = f;
    unsigned r = v.u + 0x7FFFu + ((v.u >> 16) & 1u);   // RTNE
    return (ushort_t)(r >> 16);
}
__device__ __forceinline__ float bf2f(ushort_t h) {
    union { unsigned u; float f; } v; v.u = ((unsigned)h) << 16;
    return v.f;
}

// ------- kernel 0 (fused): weight prep + trig table, coalesced writes ----
// prep part: block (m, kgp) -> thread l reads ONE 64-B pct line (16 k),
//   writes two contiguous 16-B chunks of pctwF[m][kg][l][j].
// trig part: thread -> (c,mcs): 8 sincos for one 16-B output chunk;
//   consecutive threads write consecutive chunks (fully coalesced).
__global__ __launch_bounds__(256) void prepTrigK(const float* __restrict__ pct,
                                                 const float* __restrict__ w,
                                                 const float* __restrict__ phase,
                                                 const float* __restrict__ mask,
                                                 ushort_t* __restrict__ pctwF,
                                                 ushort_t* __restrict__ Ttab3) {
    const int bid = blockIdx.x;
    const int t   = threadIdx.x;
    if (bid < NPREP) {
        // ---------------- prep: pctwF[m][kg(32)][l(256)][j(8)] ----------
        const int m   = bid >> 4;
        const int kg0 = (bid & 15) * 2;
        const int k0  = kg0 * 8;          // 0..240 step 16
        const int l   = t;
        float vals[16];
        if (l < NLAT) {
            const float* src = pct + ((size_t)m * NLAT + l) * NLAT + k0;
            if (k0 + 16 <= NLAT) {        // fast path (kgp < 15)
#pragma unroll
                for (int c = 0; c < 4; ++c) {
                    float4u pv = *(const float4u*)(src + c * 4);
                    float4v wv = *(const float4v*)(w + k0 + c * 4);
#pragma unroll
                    for (int j = 0; j < 4; ++j) vals[c * 4 + j] = pv[j] * wv[j];
                }
            } else {                      // tail (k = 255 is padding)
#pragma unroll
                for (int j = 0; j < 16; ++j) {
                    int k = k0 + j;
                    vals[j] = (k < NLAT) ? src[j] * w[k] : 0.f;
                }
            }
        } else {
#pragma unroll
            for (int j = 0; j < 16; ++j) vals[j] = 0.f;
        }
        bf16x8 h0, h1;
#pragma unroll
        for (int j = 0; j < 8; ++j) { h0[j] = (short)f2bf(vals[j]); h1[j] = (short)f2bf(vals[8 + j]); }
        *(bf16x8*)(pctwF + (((size_t)m * 32 + kg0)     * 256 + l) * 8) = h0;
        *(bf16x8*)(pctwF + (((size_t)m * 32 + kg0 + 1) * 256 + l) * 8) = h1;
    } else {
        // ---------------- trig: Ttab3[tt][pcc][c][mcs][j] ---------------
        const int idx = bid - NPREP;
        const int tt  = idx >> 2;
        const int pcc = idx & 3;
        const int r   = (tt < 63) ? tt : (tt == 63 ? 63 : 64);
        for (int i = t; i < 8 * TROWS; i += 256) {
            const int c   = i / TROWS;
            const int mcs = i - c * TROWS;
            bf16x8 h = {0,0,0,0,0,0,0,0};
            if (mcs < MCS) {
                const float fm = (float)(mcs >> 1);
#pragma unroll
                for (int j = 0; j < 8; ++j) {
                    int p = pcc * 64 + c * 8 + j;
                    float ph = phase[r * NLON + p];
                    float mk = mask[r * NLON + p];
                    float s, cs;
                    __sincosf(ph * fm, &s, &cs);
                    float val = (mcs & 1) ? (-s * mk) : (cs * mk);
                    h[j] = (short)f2bf(val);
                }
            }
            *(bf16x8*)(Ttab3 + ((((size_t)tt * 4 + pcc) * 8 + c) * TROWS + mcs) * 8) = h;
        }
    }
}

// ---------------- kernel 1: stage A (ring DFT via MFMA) ----------------
// Banked r19 structure (best): grid (4,255), lb(256,2), full-chunk
// B-prefetch bfr[4][5], T14 x-staging dbuf, wcol-cut on the ragged tile.
__global__ __launch_bounds__(256, 2) void stageA(const float* __restrict__ x,
                                                 const int* __restrict__ ring_index,
                                                 const ushort_t* __restrict__ Ttab3,
                                                 ushort_t* __restrict__ f1) {
    __shared__ __align__(16) ushort_t Rs[2][64 * 72];   // 18432 B; Olds alias

    const int b0 = blockIdx.x * 64;      // bc tile base
    const int r  = blockIdx.y;           // ring
    const int i1 = r + 1;
    const int nph = (i1 < 64) ? 4 * i1 : (i1 <= 192 ? 256 : 4 * (256 - i1));
    const int tbl = (i1 < 64) ? r : (i1 <= 192 ? (63 + (((i1 - 63) & 1) ^ 1)) : 254 - r);
    const int base = ring_index[r * NLON];
    const int nchunks = (nph + 63) >> 6;

    const int t    = threadIdx.x;
    const int lane = t & 63;
    const int wid  = t >> 6;
    const int wrow = wid >> 1, wcol = wid & 1;
    const int lg   = lane >> 5;
    const int lc   = lane & 31;

    f32x16 acc[5];
#pragma unroll
    for (int tau = 0; tau < 5; ++tau)
#pragma unroll
        for (int q = 0; q < 16; ++q) acc[tau][q] = 0.f;

    int trow[5];
#pragma unroll
    for (int tau = 0; tau < 5; ++tau) {
        int rr = tau * 64 + wcol * 32 + lc;
        trow[tau] = rr > (TROWS - 1) ? (TROWS - 1) : rr;
    }

    float4v rx[4];
    const int p0 = (t & 15) * 4;
    auto ldX = [&](int pc) {
        const bool ok = (pc + p0) < nph;
#pragma unroll
        for (int pass = 0; pass < 4; ++pass) {
            int bc = (t >> 4) + pass * 16;
            float4v v = {0.f, 0.f, 0.f, 0.f};
            if (ok) v = *(const float4v*)(x + (size_t)(b0 + bc) * NPIX + base + pc + p0);
            rx[pass] = v;
        }
    };
    auto stX = [&](ushort_t* dst) {
#pragma unroll
        for (int pass = 0; pass < 4; ++pass) {
            int bc = (t >> 4) + pass * 16;
            short4v h;
            h[0] = (short)f2bf(rx[pass][0]); h[1] = (short)f2bf(rx[pass][1]);
            h[2] = (short)f2bf(rx[pass][2]); h[3] = (short)f2bf(rx[pass][3]);
            *(short4v*)(dst + bc * 72 + p0) = h;
        }
    };

    ldX(0);
    stX(Rs[0]);
    __syncthreads();

    for (int c = 0; c < nchunks; ++c) {
        const int pc = c << 6;
        const bool more = (c + 1) < nchunks;
        const ushort_t* slab = Ttab3 + (size_t)(tbl * 4 + c) * (8 * TROWS * 8);

        bf16x8 bfr[4][5];
#pragma unroll
        for (int ks = 0; ks < 4; ++ks) {
            const ushort_t* bcol = slab + (size_t)(ks * 2 + lg) * (TROWS * 8);
#pragma unroll
            for (int tau = 0; tau < 4; ++tau)
                bfr[ks][tau] = *(const bf16x8*)(bcol + trow[tau] * 8);
            if (wcol == 0)
                bfr[ks][4] = *(const bf16x8*)(bcol + trow[4] * 8);
        }
        if (more) ldX(pc + 64);

        const ushort_t* Rcur = Rs[c & 1];
#pragma unroll
        for (int ks = 0; ks < 4; ++ks) {
            bf16x8 a = *(const bf16x8*)(Rcur + (wrow * 32 + lc) * 72 + ks * 16 + lg * 8);
#pragma unroll
            for (int tau = 0; tau < 4; ++tau)
                acc[tau] = __builtin_amdgcn_mfma_f32_32x32x16_bf16(a, bfr[ks][tau], acc[tau], 0, 0, 0);
            if (wcol == 0)
                acc[4] = __builtin_amdgcn_mfma_f32_32x32x16_bf16(a, bfr[ks][4], acc[4], 0, 0, 0);
        }
        if (more) stX(Rs[(c + 1) & 1]);
        __syncthreads();
    }

    // ---- epilogue: per tau, acc -> Olds[mcs][bc] -> coalesced f1 ----
    ushort_t* Olds = Rs[0];
#pragma unroll
    for (int tau = 0; tau < 5; ++tau) {
        __syncthreads();
        {
            const int mcsl = wcol * 32 + lc;
#pragma unroll
            for (int q = 0; q < 16; ++q) {
                int bcl = wrow * 32 + 4 * lg + (q & 3) + 8 * (q >> 2);
                Olds[mcsl * 72 + bcl] = f2bf(acc[tau][q]);
            }
        }
        __syncthreads();
        {
            int row = t >> 2;
            int mcs = tau * 64 + row;
            if (mcs < MCS) {
                int m = mcs >> 1, n = mcs & 1;
                size_t gbase = ((size_t)m * NLAT + r) * 512 + n * 256 + b0 + (t & 3) * 16;
#pragma unroll
                for (int j = 0; j < 2; ++j) {
                    bf16x8 v = *(const bf16x8*)(Olds + row * 72 + (t & 3) * 16 + j * 8);
                    *(bf16x8*)(f1 + gbase + j * 8) = v;
                }
            }
        }
    }
}

// ---------------- kernel 2: transpose f1 -> f1tF (fragment-major) -------
// f1tF[m][kg(32)][bc2(512)][j(8)]
__global__ __launch_bounds__(256) void transK(const ushort_t* __restrict__ f1,
                                              ushort_t* __restrict__ f1tF) {
    __shared__ __align__(16) ushort_t T[64][72];
    const int m  = blockIdx.x;
    const int k0 = blockIdx.y * 64;
    const int b0 = blockIdx.z * 64;
    const int t  = threadIdx.x;
#pragma unroll
    for (int it = 0; it < 2; ++it) {
        int id = t + it * 256;
        int kk = id >> 3, ch = id & 7;
        int k  = k0 + kk;
        bf16x8 v = {0,0,0,0,0,0,0,0};
        if (k < NLAT)
            v = *(const bf16x8*)(f1 + ((size_t)m * NLAT + k) * 512 + b0 + ch * 8);
        *(bf16x8*)(&T[kk][ch * 8]) = v;
    }
    __syncthreads();
#pragma unroll
    for (int it = 0; it < 2; ++it) {
        int id  = t + it * 256;
        int bb  = id & 63, ch8 = id >> 6;
        bf16x8 v;
#pragma unroll
        for (int j = 0; j < 8; ++j) v[j] = T[ch8 * 8 + j][bb];
        *(bf16x8*)(f1tF + (((size_t)m * 32 + (k0 >> 3) + ch8) * 512 + b0 + bb) * 8) = v;
    }
}

// ---------------- kernel 3: stage B v3 (m97-style gload_lds GEMM) -------
__global__ __launch_bounds__(256, 3) void stageB(const ushort_t* __restrict__ f1tF,
                                                 const ushort_t* __restrict__ pctwF,
                                                 ushort_t* __restrict__ otmp) {
    __shared__ __align__(16) ushort_t SB[24576];  // As[2][4096] | Ws[2][8192] u16
    ushort_t* Es = SB;                            // epilogue alias

    const int id = blockIdx.x;
    const int m  = ((id >> 5) << 3) | (id & 7);
    if (m >= MMAX) return;
    const int b2t = ((id >> 3) & 3) * 128;

    const int t    = threadIdx.x;
    const int lane = t & 63;
    const int wid  = t >> 6;
    const int wrow = wid >> 1, wlcol = wid & 1;
    const int lg   = lane >> 5, lc = lane & 31;

    f32x16 acc[2][4];
#pragma unroll
    for (int i = 0; i < 2; ++i)
#pragma unroll
        for (int j = 0; j < 4; ++j)
#pragma unroll
            for (int q = 0; q < 16; ++q) acc[i][j][q] = 0.f;

    const ushort_t* aSrc = f1tF  + (size_t)m * 32 * 512 * 8;
    const ushort_t* wSrc = pctwF + (size_t)m * 32 * 256 * 8;

    auto STAGE = [&](int buf, int c) {
#pragma unroll
        for (int u = 0; u < 2; ++u) {
            int sA   = wid * 2 + u;
            int kg   = c * 4 + (sA >> 1);
            int half = sA & 1;
            const ushort_t* src = aSrc + ((size_t)kg * 512 + b2t + half * 64) * 8 + lane * 8;
            __builtin_amdgcn_global_load_lds(
                (const __attribute__((address_space(1))) void*)src,
                (__attribute__((address_space(3))) void*)(SB + buf * 4096 + sA * 512),
                16, 0, 0);
        }
#pragma unroll
        for (int u = 0; u < 4; ++u) {
            int sW = wid * 4 + u;
            int kg = c * 4 + (sW >> 2);
            int q  = sW & 3;
            const ushort_t* src = wSrc + ((size_t)kg * 256 + q * 64) * 8 + lane * 8;
            __builtin_amdgcn_global_load_lds(
                (const __attribute__((address_space(1))) void*)src,
                (__attribute__((address_space(3))) void*)(SB + 8192 + buf * 8192 + sW * 512),
                16, 0, 0);
        }
    };

    STAGE(0, 0);
    __syncthreads();
    int buf = 0;
    for (int c = 0; c < 8; ++c, buf ^= 1) {
        if (c + 1 < 8) STAGE(buf ^ 1, c + 1);
        const ushort_t* A = SB + buf * 4096;
        const ushort_t* W = SB + 8192 + buf * 8192;
#pragma unroll
        for (int ks = 0; ks < 2; ++ks) {
            const int kgl = ks * 2 + lg;
            bf16x8 a0 = *(const bf16x8*)(A + (kgl * 128 + wrow * 64 + lc) * 8);
            bf16x8 a1 = *(const bf16x8*)(A + (kgl * 128 + wrow * 64 + 32 + lc) * 8);
#pragma unroll
            for (int jj = 0; jj < 4; ++jj) {
                bf16x8 b = *(const bf16x8*)(W + (kgl * 256 + wlcol * 128 + jj * 32 + lc) * 8);
                acc[0][jj] = __builtin_amdgcn_mfma_f32_32x32x16_bf16(a0, b, acc[0][jj], 0, 0, 0);
                acc[1][jj] = __builtin_amdgcn_mfma_f32_32x32x16_bf16(a1, b, acc[1][jj], 0, 0, 0);
            }
        }
        __syncthreads();
    }

#pragma unroll
    for (int h = 0; h < 2; ++h) {
        if (h) __syncthreads();
        if (wlcol == h) {
#pragma unroll
            for (int i = 0; i < 2; ++i)
#pragma unroll
                for (int jj = 0; jj < 4; ++jj)
#pragma unroll
                    for (int q = 0; q < 16; ++q) {
                        int bl = wrow * 64 + i * 32 + 4 * lg + (q & 3) + 8 * (q >> 2);
                        Es[bl * 136 + jj * 32 + lc] = f2bf(acc[i][jj][q]);
                    }
        }
        __syncthreads();
#pragma unroll
        for (int it = 0; it < 8; ++it) {
            int id2 = t + it * 256;
            int row = id2 >> 4, ch = id2 & 15;
            bf16x8 v = *(const bf16x8*)(Es + row * 136 + ch * 8);
            *(bf16x8*)(otmp + (((size_t)m * 512 + b2t + row) << 8) + h * 128 + ch * 8) = v;
        }
    }
}

// ---------------- kernel 4: permute to out[bc][l][m][n] ----------------
__global__ __launch_bounds__(256) void permuteK(const ushort_t* __restrict__ otmp,
                                                float* __restrict__ out) {
    __shared__ ushort_t L[MCS * 66];
    const int bc = blockIdx.x;
    const int l0 = blockIdx.y * 64;
    const int t  = threadIdx.x;
    const int ll = t & 63;
    const int l  = l0 + ll;
#pragma unroll 4
    for (int it = 0; it < 65; ++it) {
        int mn = (t >> 6) + it * 4;
        if (mn < MCS) {
            int mm = mn >> 1, n = mn & 1;
            ushort_t v = 0;
            if (l < NLAT)
                v = otmp[(((size_t)mm * 512 + n * 256 + bc) << 8) + l];
            L[mn * 66 + ll] = v;
        }
    }
    __syncthreads();
    for (int ll2 = 0; ll2 < 64; ++ll2) {
        int lo = l0 + ll2;
        if (lo >= NLAT) break;
        size_t rowb = ((size_t)bc * NLAT + lo) * MCS;
        out[rowb + t] = bf2f(L[t * 66 + ll2]);
        if (t < 2)
            out[rowb + 256 + t] = bf2f(L[(256 + t) * 66 + ll2]);
    }
}

extern "C" void kernel_launch(void* const* d_in, const int* in_sizes, int n_in,
                              void* d_out, int out_size, void* d_ws, size_t ws_size,
                              hipStream_t stream) {
    const float* x          = (const float*)d_in[0];
    const float* pct        = (const float*)d_in[1];
    const float* w          = (const float*)d_in[2];
    const int*   ring_index = (const int*)d_in[3];
    const float* ring_mask  = (const float*)d_in[4];
    const float* phase      = (const float*)d_in[5];
    float* out = (float*)d_out;

    // Buffer plan (NO intra-launch hazards):
    //   ws   : otmp @ 0; f1 @ 33,552,384 (otmp tail overlaps dead f1 head).
    //   d_out: f1tF @ 0; pctwF @ 33,816,576; Ttab3 @ 50,724,864 — all dead
    //          before permuteK overwrites d_out with the real output.
    char* wsb = (char*)d_ws;
    char* ob  = (char*)d_out;
    ushort_t* otmp  = (ushort_t*)wsb;
    ushort_t* f1    = (ushort_t*)(wsb + 33552384);
    ushort_t* f1tF  = (ushort_t*)ob;
    ushort_t* pctwF = (ushort_t*)(ob + 33816576);
    ushort_t* Ttab3 = (ushort_t*)(ob + 50724864);

    prepTrigK<<<dim3(NPREP + NTBL * 4), 256, 0, stream>>>(pct, w, phase, ring_mask,
                                                          pctwF, Ttab3);
    stageA  <<<dim3(4, NLAT),     256, 0, stream>>>(x, ring_index, Ttab3, f1);
    transK  <<<dim3(MMAX, 4, 8),  256, 0, stream>>>(f1, f1tF);
    stageB  <<<dim3(544),         256, 0, stream>>>(f1tF, pctwF, otmp);
    permuteK<<<dim3(256, 4),      256, 0, stream>>>(otmp, out);
}